// Round 6
// baseline (162.674 us; speedup 1.0000x reference)
//
#include <hip/hip_runtime.h>
#include <hip/hip_bf16.h>

// DeepQNetwork MoE as a sorted grouped GEMM with split-bf16 MFMA.
// R6: 32x32x16 MFMA (halves B-frag bytes/row), 8-wave blocks (4 m-tiles x 2
// K-halves = 128 rows), explicit next-layer weight-fragment prefetch.

#define NE   8
#define DIM  256
#define HID  64
#define NA   18

typedef __attribute__((ext_vector_type(8)))  short short8;
typedef __attribute__((ext_vector_type(16))) float f32x16;
#define MFMA32 __builtin_amdgcn_mfma_f32_32x32x16_bf16

// ---------- bf16 split helpers ----------
__device__ __forceinline__ unsigned short f2bf(float f) {     // RNE scalar
    unsigned u = __builtin_bit_cast(unsigned, f);
    u += 0x7fff + ((u >> 16) & 1);
    return (unsigned short)(u >> 16);
}
__device__ __forceinline__ float bf2f(unsigned short h) {
    unsigned u = ((unsigned)h) << 16;
    return __builtin_bit_cast(float, u);
}
__device__ __forceinline__ void split8v(const float* xs, short8& hi, short8& lo) {
    float back[8];
    #pragma unroll
    for (int p = 0; p < 4; ++p) {
        __hip_bfloat162 h2 = __float22bfloat162_rn(make_float2(xs[2*p], xs[2*p+1]));
        hi[2*p]   = (short)__builtin_bit_cast(unsigned short, h2.x);
        hi[2*p+1] = (short)__builtin_bit_cast(unsigned short, h2.y);
        float2 b2 = __bfloat1622float2(h2);
        back[2*p] = b2.x; back[2*p+1] = b2.y;
    }
    #pragma unroll
    for (int p = 0; p < 4; ++p) {
        __hip_bfloat162 l2 = __float22bfloat162_rn(
            make_float2(xs[2*p] - back[2*p], xs[2*p+1] - back[2*p+1]));
        lo[2*p]   = (short)__builtin_bit_cast(unsigned short, l2.x);
        lo[2*p+1] = (short)__builtin_bit_cast(unsigned short, l2.y);
    }
}

// ---------- kernel 1: weight frag (8 elems/thread, 32x32x16 layout) + histogram ----------
// frag: lane l holds B[k][n], n = nt*32 + (l&31), k = ks*16 + (l>>5)*8 + j.
// storage: expert base + ((ksg*NNT + nt)*64 + l)*8
// units: W1 16384, W2..5 4096 ea, W6 2048  -> 34816 = 136 blocks; histo [136,392)
__global__ __launch_bounds__(256) void prep_histo(
    const float* __restrict__ W1, const float* __restrict__ W2,
    const float* __restrict__ W3, const float* __restrict__ W4,
    const float* __restrict__ W5, const float* __restrict__ W6,
    short* __restrict__ W1H, short* __restrict__ W1L,
    short* __restrict__ W2H, short* __restrict__ W2L,
    short* __restrict__ W3H, short* __restrict__ W3L,
    short* __restrict__ W4H, short* __restrict__ W4L,
    short* __restrict__ W5H, short* __restrict__ W5L,
    short* __restrict__ W6H, short* __restrict__ W6L,
    const int* __restrict__ rm, int* __restrict__ hist) {
    const int bid = blockIdx.x;
    if (bid >= 136) {                         // ---- histogram ----
        __shared__ int wch[4][NE];
        const int blk = bid - 136;
        const int t = threadIdx.x, w = t >> 6, l = t & 63;
        const int e = rm[blk * 256 + t];
        #pragma unroll
        for (int q = 0; q < NE; ++q) {
            unsigned long long m = __ballot(e == q);
            if (l == 0) wch[w][q] = __popcll(m);
        }
        __syncthreads();
        if (t < NE) hist[blk * NE + t] = wch[0][t] + wch[1][t] + wch[2][t] + wch[3][t];
        return;
    }
    const int u = bid * 256 + threadIdx.x;    // ---- prep ----
    const float* src; int sstride, dbase, n, npad;
    short *H, *L;
    if (u < 16384) {                          // W1: e(3) ks(4,16) nt(1) l(6)
        int e = u >> 11, r = u & 2047;
        int ks = r >> 7, nt = (r >> 6) & 1, l = r & 63;
        int k0 = ks * 16 + ((l >> 5) << 3); n = (nt << 5) + (l & 31);
        src = W1 + ((size_t)(e * DIM + k0)) * HID + n;
        sstride = HID; npad = HID;
        H = W1H; L = W1L; dbase = e * 16384 + ((ks * 2 + nt) * 64 + l) * 8;
    } else if (u < 32768) {                   // W2..5: layer(2) e(3) ks(2,4) nt(1) l(6)
        int u2 = u - 16384;
        int layer = u2 >> 12, local = u2 & 4095;
        int e = local >> 9, r = local & 511;
        int ks = r >> 7, nt = (r >> 6) & 1, l = r & 63;
        int k0 = ks * 16 + ((l >> 5) << 3); n = (nt << 5) + (l & 31);
        const float* W = (layer == 0) ? W2 : (layer == 1) ? W3 : (layer == 2) ? W4 : W5;
        src = W + ((size_t)(e * HID + k0)) * HID + n;
        sstride = HID; npad = HID;
        H = (layer == 0) ? W2H : (layer == 1) ? W3H : (layer == 2) ? W4H : W5H;
        L = (layer == 0) ? W2L : (layer == 1) ? W3L : (layer == 2) ? W4L : W5L;
        dbase = e * 4096 + ((ks * 2 + nt) * 64 + l) * 8;
    } else {                                  // W6: e(3) ks(2,4) l(6), N pad 18->32, 1 nt
        int u3 = u - 32768;
        int e = u3 >> 8, r = u3 & 255;
        int ks = r >> 6, l = r & 63;
        int k0 = ks * 16 + ((l >> 5) << 3); n = l & 31;
        src = W6 + ((size_t)(e * HID + k0)) * NA + n;
        sstride = NA; npad = NA;
        H = W6H; L = W6L; dbase = e * 2048 + (ks * 64 + l) * 8;
    }
    short8 hs, ls;
    #pragma unroll
    for (int j = 0; j < 8; ++j) {
        float v = (n < npad) ? src[j * sstride] : 0.0f;
        unsigned short h = f2bf(v);
        hs[j] = (short)h;
        ls[j] = (short)f2bf(v - bf2f(h));
    }
    *(short8*)(H + dbase) = hs;
    *(short8*)(L + dbase) = ls;
}

// ---------- kernel 2: fused scan + scatter ----------
// meta[0..7]=counts  meta[8..16]=expertStart  meta[17..25]=tile128Start
__global__ __launch_bounds__(512) void scan_scatter(const int* __restrict__ rm,
                                                    const int* __restrict__ hist,
                                                    int* __restrict__ perm,
                                                    int* __restrict__ meta) {
    __shared__ int sbuf[NE][256];
    __shared__ int wc[8][NE];
    __shared__ int wb2[4][NE];
    __shared__ int baseE[NE];
    const int t = threadIdx.x, w = t >> 6, l = t & 63;
    const int myblk = blockIdx.x;

    {   // scan: wave w handles expert w
        int v0 = hist[(l * 4 + 0) * NE + w];
        int v1 = hist[(l * 4 + 1) * NE + w];
        int v2 = hist[(l * 4 + 2) * NE + w];
        int v3 = hist[(l * 4 + 3) * NE + w];
        v1 += v0; v2 += v1; v3 += v2;
        int s = v3;
        #pragma unroll
        for (int off = 1; off < 64; off <<= 1) {
            int u = __shfl_up(s, off);
            if (l >= off) s += u;
        }
        const int ex = s - v3;
        sbuf[w][l * 4 + 0] = ex + v0;
        sbuf[w][l * 4 + 1] = ex + v1;
        sbuf[w][l * 4 + 2] = ex + v2;
        sbuf[w][l * 4 + 3] = ex + v3;
    }
    __syncthreads();
    if (t < NE) {
        int es = 0;
        for (int q = 0; q < t; ++q) es += sbuf[q][255];
        baseE[t] = es + (myblk ? sbuf[t][myblk - 1] : 0);
    }
    if (myblk == 0 && t == 0) {
        int es = 0, ts = 0;
        meta[8] = 0; meta[17] = 0;
        for (int e = 0; e < NE; ++e) {
            int c = sbuf[e][255];
            meta[e] = c;
            es += c; meta[8 + e + 1] = es;
            ts += (c + 127) >> 7; meta[17 + e + 1] = ts;   // 128-row tiles
        }
    }
    const int i = myblk * 256 + t;
    const int e_row = (t < 256) ? rm[i] : -1;
    const unsigned long long ltm = (1ull << l) - 1ull;
    int rank = 0;
    #pragma unroll
    for (int q = 0; q < NE; ++q) {
        unsigned long long m = __ballot(e_row == q);
        if (e_row == q) rank = __popcll(m & ltm);
        if (l == 0) wc[w][q] = __popcll(m);
    }
    __syncthreads();
    if (t < 32) {
        int ww = t >> 3, q = t & 7;
        int b = baseE[q];
        for (int p = 0; p < ww; ++p) b += wc[p][q];
        wb2[ww][q] = b;
    }
    __syncthreads();
    if (t < 256) perm[wb2[w][e_row] + rank] = i;
}

// ---------- kernel 3: 32x32x16 K-split MFMA MLP ----------
__device__ __forceinline__ void rs(const float* pa, const float* pb, int off,
                                   short8& hi, short8& lo) {
    float4 a0 = *(const float4*)(pa + off);
    float4 a1 = *(const float4*)(pa + off + 4);
    float4 b0 = *(const float4*)(pb + off);
    float4 b1 = *(const float4*)(pb + off + 4);
    float xs[8] = {fmaxf(a0.x + b0.x, 0.0f), fmaxf(a0.y + b0.y, 0.0f),
                   fmaxf(a0.z + b0.z, 0.0f), fmaxf(a0.w + b0.w, 0.0f),
                   fmaxf(a1.x + b1.x, 0.0f), fmaxf(a1.y + b1.y, 0.0f),
                   fmaxf(a1.z + b1.z, 0.0f), fmaxf(a1.w + b1.w, 0.0f)};
    split8v(xs, hi, lo);
}

// D: col = lane&31, row = (reg&3) + 8*(reg>>2) + 4*(lane>>5)   [m74/m101]
__device__ __forceinline__ void write16(float* pw, int lc, int lh,
                                        const float* bias,
                                        const f32x16& c0, const f32x16& c1) {
    #pragma unroll
    for (int nt = 0; nt < 2; ++nt) {
        const f32x16& c = nt ? c1 : c0;
        float bv = bias ? bias[nt * 32 + lc] : 0.0f;
        #pragma unroll
        for (int r = 0; r < 16; ++r) {
            int rw = (r & 3) + 8 * (r >> 2) + 4 * lh;
            pw[rw * 66 + nt * 32 + lc] = c[r] + bv;
        }
    }
}
__device__ __forceinline__ void write16_1(float* pw, int lc, int lh,
                                          const f32x16& c0) {
    #pragma unroll
    for (int r = 0; r < 16; ++r) {
        int rw = (r & 3) + 8 * (r >> 2) + 4 * lh;
        pw[rw * 66 + lc] = c0[r];
    }
}

#define PF4(nm, ph, pl)                                    \
    nm##h0 = *(const short8*)(ph);                         \
    nm##h1 = *(const short8*)((ph) + 512);                 \
    nm##h2 = *(const short8*)((ph) + 1024);                \
    nm##h3 = *(const short8*)((ph) + 1536);                \
    nm##l0 = *(const short8*)(pl);                         \
    nm##l1 = *(const short8*)((pl) + 512);                 \
    nm##l2 = *(const short8*)((pl) + 1024);                \
    nm##l3 = *(const short8*)((pl) + 1536);

// frag q=ks*2+nt: q0:(ks0,nt0) q1:(ks0,nt1) q2:(ks1,nt0) q3:(ks1,nt1)
#define HIDDEN(nm, PREFETCH, biasp)                                           \
    {                                                                         \
        short8 a0h, a0l, a1h, a1l;                                            \
        rs(pa, pb, roff, a0h, a0l);                                           \
        rs(pa, pb, roff + 16, a1h, a1l);                                      \
        PREFETCH                                                              \
        __syncthreads();                                                      \
        f32x16 c0 = {}, c1 = {};                                              \
        c0 = MFMA32(a0h, nm##h0, c0, 0, 0, 0);                                \
        c0 = MFMA32(a0l, nm##h0, c0, 0, 0, 0);                                \
        c0 = MFMA32(a0h, nm##l0, c0, 0, 0, 0);                                \
        c1 = MFMA32(a0h, nm##h1, c1, 0, 0, 0);                                \
        c1 = MFMA32(a0l, nm##h1, c1, 0, 0, 0);                                \
        c1 = MFMA32(a0h, nm##l1, c1, 0, 0, 0);                                \
        c0 = MFMA32(a1h, nm##h2, c0, 0, 0, 0);                                \
        c0 = MFMA32(a1l, nm##h2, c0, 0, 0, 0);                                \
        c0 = MFMA32(a1h, nm##l2, c0, 0, 0, 0);                                \
        c1 = MFMA32(a1h, nm##h3, c1, 0, 0, 0);                                \
        c1 = MFMA32(a1l, nm##h3, c1, 0, 0, 0);                                \
        c1 = MFMA32(a1h, nm##l3, c1, 0, 0, 0);                                \
        write16(pw, lc, lh, biasp, c0, c1);                                   \
        __syncthreads();                                                      \
    }

__global__ __launch_bounds__(512, 4) void mlp_mfma(
    const float* __restrict__ x, const int* __restrict__ perm,
    const int* __restrict__ meta,
    const short* __restrict__ W1H, const short* __restrict__ W1L,
    const short* __restrict__ W2H, const short* __restrict__ W2L,
    const short* __restrict__ W3H, const short* __restrict__ W3L,
    const short* __restrict__ W4H, const short* __restrict__ W4L,
    const short* __restrict__ W5H, const short* __restrict__ W5L,
    const short* __restrict__ W6H, const short* __restrict__ W6L,
    const float* __restrict__ b1, const float* __restrict__ b2,
    const float* __restrict__ b3, const float* __restrict__ b4,
    const float* __restrict__ b5, const float* __restrict__ b6,
    float* __restrict__ out) {
    __shared__ __align__(16) float hbuf[2][4][32][66];   // 67584 B
    const int blk = blockIdx.x;
    if (blk >= meta[17 + NE]) return;
    int e = 0;
    #pragma unroll 1
    while (blk >= meta[17 + e + 1]) ++e;
    const int lt = blk - meta[17 + e];
    const int cnt = meta[e];
    const int pbase = meta[8 + e];
    const int t = threadIdx.x, w = t >> 6, l = t & 63;
    const int m = w >> 1, kh = w & 1;
    const int lc = l & 31, lh = l >> 5;
    const int li = lt * 128 + m * 32 + lc;
    const int row = perm[pbase + min(li, cnt - 1)];

    float* pw = &hbuf[kh][m][0][0];
    const float* pa = &hbuf[0][m][0][0];
    const float* pb = &hbuf[1][m][0][0];
    const int roff = lc * 66 + kh * 32 + lh * 8;

    // per-wave fragment base pointers (kh-sliced)
    const short* pW1h = W1H + e * 16384 + kh * 8192 + l * 8;
    const short* pW1l = W1L + e * 16384 + kh * 8192 + l * 8;
    const short* pW2h = W2H + e * 4096 + kh * 2048 + l * 8;
    const short* pW2l = W2L + e * 4096 + kh * 2048 + l * 8;
    const short* pW3h = W3H + e * 4096 + kh * 2048 + l * 8;
    const short* pW3l = W3L + e * 4096 + kh * 2048 + l * 8;
    const short* pW4h = W4H + e * 4096 + kh * 2048 + l * 8;
    const short* pW4l = W4L + e * 4096 + kh * 2048 + l * 8;
    const short* pW5h = W5H + e * 4096 + kh * 2048 + l * 8;
    const short* pW5l = W5L + e * 4096 + kh * 2048 + l * 8;
    const short* pW6h = W6H + e * 2048 + kh * 1024 + l * 8;
    const short* pW6l = W6L + e * 2048 + kh * 1024 + l * 8;

    // prefetch registers for next-layer fragments
    short8 f2h0, f2h1, f2h2, f2h3, f2l0, f2l1, f2l2, f2l3;
    short8 f3h0, f3h1, f3h2, f3h3, f3l0, f3l1, f3l2, f3l3;
    short8 f4h0, f4h1, f4h2, f4h3, f4l0, f4l1, f4l2, f4l3;
    short8 f5h0, f5h1, f5h2, f5h3, f5l0, f5l1, f5l2, f5l3;
    short8 f6h0, f6h1, f6l0, f6l1;

    // ---- layer 1: x[row][256] @ W1, wave covers k in [kh*128, kh*128+128) ----
    {
        f32x16 c0 = {}, c1 = {};
        const float* xr = x + (size_t)row * DIM + kh * 128 + lh * 8;
        #pragma unroll
        for (int ks = 0; ks < 8; ++ks) {
            float4 u0 = *(const float4*)(xr + ks * 16);
            float4 u1 = *(const float4*)(xr + ks * 16 + 4);
            float xs[8] = {u0.x, u0.y, u0.z, u0.w, u1.x, u1.y, u1.z, u1.w};
            short8 ah, al; split8v(xs, ah, al);
            short8 bh0 = *(const short8*)(pW1h + (ks * 2 + 0) * 512);
            short8 bl0 = *(const short8*)(pW1l + (ks * 2 + 0) * 512);
            short8 bh1 = *(const short8*)(pW1h + (ks * 2 + 1) * 512);
            short8 bl1 = *(const short8*)(pW1l + (ks * 2 + 1) * 512);
            c0 = MFMA32(ah, bh0, c0, 0, 0, 0);
            c0 = MFMA32(al, bh0, c0, 0, 0, 0);
            c0 = MFMA32(ah, bl0, c0, 0, 0, 0);
            c1 = MFMA32(ah, bh1, c1, 0, 0, 0);
            c1 = MFMA32(al, bh1, c1, 0, 0, 0);
            c1 = MFMA32(ah, bl1, c1, 0, 0, 0);
        }
        PF4(f2, pW2h, pW2l)
        write16(pw, lc, lh, (kh == 0) ? b1 + e * HID : nullptr, c0, c1);
        __syncthreads();
    }

    // ---- layers 2..5 (K=64, wave covers k in [kh*32, kh*32+32)) ----
    HIDDEN(f2, PF4(f3, pW3h, pW3l), (kh == 0) ? b2 + e * HID : nullptr)
    HIDDEN(f3, PF4(f4, pW4h, pW4l), (kh == 0) ? b3 + e * HID : nullptr)
    HIDDEN(f4, PF4(f5, pW5h, pW5l), (kh == 0) ? b4 + e * HID : nullptr)
    HIDDEN(f5,
           f6h0 = *(const short8*)(pW6h);
           f6h1 = *(const short8*)(pW6h + 512);
           f6l0 = *(const short8*)(pW6l);
           f6l1 = *(const short8*)(pW6l + 512);,
           (kh == 0) ? b5 + e * HID : nullptr)

    // ---- layer 6: K=64 -> 32 cols (18 used) ----
    {
        short8 a0h, a0l, a1h, a1l;
        rs(pa, pb, roff, a0h, a0l);
        rs(pa, pb, roff + 16, a1h, a1l);
        __syncthreads();
        f32x16 c0 = {};
        c0 = MFMA32(a0h, f6h0, c0, 0, 0, 0);
        c0 = MFMA32(a0l, f6h0, c0, 0, 0, 0);
        c0 = MFMA32(a0h, f6l0, c0, 0, 0, 0);
        c0 = MFMA32(a1h, f6h1, c0, 0, 0, 0);
        c0 = MFMA32(a1l, f6h1, c0, 0, 0, 0);
        c0 = MFMA32(a1h, f6l1, c0, 0, 0, 0);
        write16_1(pw, lc, lh, c0);
        __syncthreads();
    }

    // ---- store: 4 m-tiles x 32 rows x 18 cols, partials summed + b6 ----
    const float* b6p = b6 + e * NA;
    for (int idx = t; idx < 4 * 32 * NA; idx += 512) {
        const int m2 = idx / (32 * NA);
        const int rr = (idx / NA) % 32;
        const int c  = idx % NA;
        const int gr = lt * 128 + m2 * 32 + rr;
        if (gr < cnt) {
            const int rowid = perm[pbase + gr];
            out[(size_t)rowid * NA + c] =
                hbuf[0][m2][rr][c] + hbuf[1][m2][rr][c] + b6p[c];
        }
    }
}

extern "C" void kernel_launch(void* const* d_in, const int* in_sizes, int n_in,
                              void* d_out, int out_size, void* d_ws, size_t ws_size,
                              hipStream_t stream) {
    const float* x  = (const float*)d_in[0];
    const int*   rm = (const int*)d_in[1];
    const float* W1 = (const float*)d_in[2];   const float* b1 = (const float*)d_in[3];
    const float* W2 = (const float*)d_in[4];   const float* b2 = (const float*)d_in[5];
    const float* W3 = (const float*)d_in[6];   const float* b3 = (const float*)d_in[7];
    const float* W4 = (const float*)d_in[8];   const float* b4 = (const float*)d_in[9];
    const float* W5 = (const float*)d_in[10];  const float* b5 = (const float*)d_in[11];
    const float* W6 = (const float*)d_in[12];  const float* b6 = (const float*)d_in[13];
    float* out = (float*)d_out;

    const int B = in_sizes[1];                 // 65536
    const int nblk = B / 256;                  // 256

    // ws layout:
    int* hist = (int*)d_ws;                    // nblk*8
    int* meta = hist + nblk * NE;              // 32
    int* perm = meta + 32;                     // B
    short* W1H = (short*)(perm + B);           // frag buffers
    short* W1L = W1H + 131072;
    short* W2H = W1L + 131072;  short* W2L = W2H + 32768;
    short* W3H = W2L + 32768;   short* W3L = W3H + 32768;
    short* W4H = W3L + 32768;   short* W4L = W4H + 32768;
    short* W5H = W4L + 32768;   short* W5L = W5H + 32768;
    short* W6H = W5L + 32768;   short* W6L = W6H + 16384;

    prep_histo<<<136 + nblk, 256, 0, stream>>>(W1, W2, W3, W4, W5, W6,
                                               W1H, W1L, W2H, W2L, W3H, W3L,
                                               W4H, W4L, W5H, W5L, W6H, W6L,
                                               rm, hist);
    scan_scatter<<<nblk, 512, 0, stream>>>(rm, hist, perm, meta);
    mlp_mfma<<<B / 128 + NE, 512, 0, stream>>>(x, perm, meta,
                                               W1H, W1L, W2H, W2L, W3H, W3L,
                                               W4H, W4L, W5H, W5L, W6H, W6L,
                                               b1, b2, b3, b4, b5, b6, out);
}

// Round 7
// 153.411 us; speedup vs baseline: 1.0604x; 1.0604x over previous
//
#include <hip/hip_runtime.h>
#include <hip/hip_bf16.h>

// DeepQNetwork MoE as a sorted grouped GEMM with split-bf16 MFMA.
// R7: weight fragments staged into double-buffered LDS (17 steps x 8 KB),
// shared by all 4 waves of the block -> 4x less L2 fragment traffic.
// Block = 4 waves x 32 rows (32x32x16 MFMA, full K per wave, private hbuf).

#define NE   8
#define DIM  256
#define HID  64
#define NA   18

typedef __attribute__((ext_vector_type(8)))  short short8;
typedef __attribute__((ext_vector_type(16))) float f32x16;
#define MFMA32 __builtin_amdgcn_mfma_f32_32x32x16_bf16

// ---------- bf16 split helpers ----------
__device__ __forceinline__ unsigned short f2bf(float f) {     // RNE scalar
    unsigned u = __builtin_bit_cast(unsigned, f);
    u += 0x7fff + ((u >> 16) & 1);
    return (unsigned short)(u >> 16);
}
__device__ __forceinline__ float bf2f(unsigned short h) {
    unsigned u = ((unsigned)h) << 16;
    return __builtin_bit_cast(float, u);
}
__device__ __forceinline__ void split8v(const float* xs, short8& hi, short8& lo) {
    float back[8];
    #pragma unroll
    for (int p = 0; p < 4; ++p) {
        __hip_bfloat162 h2 = __float22bfloat162_rn(make_float2(xs[2*p], xs[2*p+1]));
        hi[2*p]   = (short)__builtin_bit_cast(unsigned short, h2.x);
        hi[2*p+1] = (short)__builtin_bit_cast(unsigned short, h2.y);
        float2 b2 = __bfloat1622float2(h2);
        back[2*p] = b2.x; back[2*p+1] = b2.y;
    }
    #pragma unroll
    for (int p = 0; p < 4; ++p) {
        __hip_bfloat162 l2 = __float22bfloat162_rn(
            make_float2(xs[2*p] - back[2*p], xs[2*p+1] - back[2*p+1]));
        lo[2*p]   = (short)__builtin_bit_cast(unsigned short, l2.x);
        lo[2*p+1] = (short)__builtin_bit_cast(unsigned short, l2.y);
    }
}

// ---------- kernel 1: weight frag (32x32x16 layout) + histogram ----------
// frag: lane l holds B[k][n], n = nt*32 + (l&31), k = ks*16 + (l>>5)*8 + j.
__global__ __launch_bounds__(256) void prep_histo(
    const float* __restrict__ W1, const float* __restrict__ W2,
    const float* __restrict__ W3, const float* __restrict__ W4,
    const float* __restrict__ W5, const float* __restrict__ W6,
    short* __restrict__ W1H, short* __restrict__ W1L,
    short* __restrict__ W2H, short* __restrict__ W2L,
    short* __restrict__ W3H, short* __restrict__ W3L,
    short* __restrict__ W4H, short* __restrict__ W4L,
    short* __restrict__ W5H, short* __restrict__ W5L,
    short* __restrict__ W6H, short* __restrict__ W6L,
    const int* __restrict__ rm, int* __restrict__ hist) {
    const int bid = blockIdx.x;
    if (bid >= 136) {                         // ---- histogram ----
        __shared__ int wch[4][NE];
        const int blk = bid - 136;
        const int t = threadIdx.x, w = t >> 6, l = t & 63;
        const int e = rm[blk * 256 + t];
        #pragma unroll
        for (int q = 0; q < NE; ++q) {
            unsigned long long m = __ballot(e == q);
            if (l == 0) wch[w][q] = __popcll(m);
        }
        __syncthreads();
        if (t < NE) hist[blk * NE + t] = wch[0][t] + wch[1][t] + wch[2][t] + wch[3][t];
        return;
    }
    const int u = bid * 256 + threadIdx.x;    // ---- prep ----
    const float* src; int sstride, dbase, n, npad;
    short *H, *L;
    if (u < 16384) {                          // W1: e(3) ks(4,16) nt(1) l(6)
        int e = u >> 11, r = u & 2047;
        int ks = r >> 7, nt = (r >> 6) & 1, l = r & 63;
        int k0 = ks * 16 + ((l >> 5) << 3); n = (nt << 5) + (l & 31);
        src = W1 + ((size_t)(e * DIM + k0)) * HID + n;
        sstride = HID; npad = HID;
        H = W1H; L = W1L; dbase = e * 16384 + ((ks * 2 + nt) * 64 + l) * 8;
    } else if (u < 32768) {                   // W2..5: layer(2) e(3) ks(2,4) nt(1) l(6)
        int u2 = u - 16384;
        int layer = u2 >> 12, local = u2 & 4095;
        int e = local >> 9, r = local & 511;
        int ks = r >> 7, nt = (r >> 6) & 1, l = r & 63;
        int k0 = ks * 16 + ((l >> 5) << 3); n = (nt << 5) + (l & 31);
        const float* W = (layer == 0) ? W2 : (layer == 1) ? W3 : (layer == 2) ? W4 : W5;
        src = W + ((size_t)(e * HID + k0)) * HID + n;
        sstride = HID; npad = HID;
        H = (layer == 0) ? W2H : (layer == 1) ? W3H : (layer == 2) ? W4H : W5H;
        L = (layer == 0) ? W2L : (layer == 1) ? W3L : (layer == 2) ? W4L : W5L;
        dbase = e * 4096 + ((ks * 2 + nt) * 64 + l) * 8;
    } else {                                  // W6: e(3) ks(2,4) l(6), N pad 18->32
        int u3 = u - 32768;
        int e = u3 >> 8, r = u3 & 255;
        int ks = r >> 6, l = r & 63;
        int k0 = ks * 16 + ((l >> 5) << 3); n = l & 31;
        src = W6 + ((size_t)(e * HID + k0)) * NA + n;
        sstride = NA; npad = NA;
        H = W6H; L = W6L; dbase = e * 2048 + (ks * 64 + l) * 8;
    }
    short8 hs, ls;
    #pragma unroll
    for (int j = 0; j < 8; ++j) {
        float v = (n < npad) ? src[j * sstride] : 0.0f;
        unsigned short h = f2bf(v);
        hs[j] = (short)h;
        ls[j] = (short)f2bf(v - bf2f(h));
    }
    *(short8*)(H + dbase) = hs;
    *(short8*)(L + dbase) = ls;
}

// ---------- kernel 2: fused scan + scatter ----------
// meta[0..7]=counts  meta[8..16]=expertStart  meta[17..25]=tile128Start
__global__ __launch_bounds__(512) void scan_scatter(const int* __restrict__ rm,
                                                    const int* __restrict__ hist,
                                                    int* __restrict__ perm,
                                                    int* __restrict__ meta) {
    __shared__ int sbuf[NE][256];
    __shared__ int wc[8][NE];
    __shared__ int wb2[4][NE];
    __shared__ int baseE[NE];
    const int t = threadIdx.x, w = t >> 6, l = t & 63;
    const int myblk = blockIdx.x;

    {   // scan: wave w handles expert w
        int v0 = hist[(l * 4 + 0) * NE + w];
        int v1 = hist[(l * 4 + 1) * NE + w];
        int v2 = hist[(l * 4 + 2) * NE + w];
        int v3 = hist[(l * 4 + 3) * NE + w];
        v1 += v0; v2 += v1; v3 += v2;
        int s = v3;
        #pragma unroll
        for (int off = 1; off < 64; off <<= 1) {
            int u = __shfl_up(s, off);
            if (l >= off) s += u;
        }
        const int ex = s - v3;
        sbuf[w][l * 4 + 0] = ex + v0;
        sbuf[w][l * 4 + 1] = ex + v1;
        sbuf[w][l * 4 + 2] = ex + v2;
        sbuf[w][l * 4 + 3] = ex + v3;
    }
    __syncthreads();
    if (t < NE) {
        int es = 0;
        for (int q = 0; q < t; ++q) es += sbuf[q][255];
        baseE[t] = es + (myblk ? sbuf[t][myblk - 1] : 0);
    }
    if (myblk == 0 && t == 0) {
        int es = 0, ts = 0;
        meta[8] = 0; meta[17] = 0;
        for (int e = 0; e < NE; ++e) {
            int c = sbuf[e][255];
            meta[e] = c;
            es += c; meta[8 + e + 1] = es;
            ts += (c + 127) >> 7; meta[17 + e + 1] = ts;   // 128-row tiles
        }
    }
    const int i = myblk * 256 + t;
    const int e_row = (t < 256) ? rm[i] : -1;
    const unsigned long long ltm = (1ull << l) - 1ull;
    int rank = 0;
    #pragma unroll
    for (int q = 0; q < NE; ++q) {
        unsigned long long m = __ballot(e_row == q);
        if (e_row == q) rank = __popcll(m & ltm);
        if (l == 0) wc[w][q] = __popcll(m);
    }
    __syncthreads();
    if (t < 32) {
        int ww = t >> 3, q = t & 7;
        int b = baseE[q];
        for (int p = 0; p < ww; ++p) b += wc[p][q];
        wb2[ww][q] = b;
    }
    __syncthreads();
    if (t < 256) perm[wb2[w][e_row] + rank] = i;
}

// ---------- kernel 3: LDS-staged-weights MFMA MLP ----------
// 17 steps x 8 KB (hi 4KB + lo 4KB), double-buffered frag LDS, 1 barrier/step.
// steps 0-7: W1 chunks; 8-15: W2..W5 (2 each); 16: W6.
__global__ __launch_bounds__(256, 3) void mlp_mfma(
    const float* __restrict__ x, const int* __restrict__ perm,
    const int* __restrict__ meta,
    const short* __restrict__ W1H, const short* __restrict__ W1L,
    const short* __restrict__ W2H, const short* __restrict__ W2L,
    const short* __restrict__ W3H, const short* __restrict__ W3L,
    const short* __restrict__ W4H, const short* __restrict__ W4L,
    const short* __restrict__ W5H, const short* __restrict__ W5L,
    const short* __restrict__ W6H, const short* __restrict__ W6L,
    const float* __restrict__ b1, const float* __restrict__ b2,
    const float* __restrict__ b3, const float* __restrict__ b4,
    const float* __restrict__ b5, const float* __restrict__ b6,
    float* __restrict__ out) {
    __shared__ __align__(16) float hbuf[4][32][66];   // 33792 B, wave-private h
    __shared__ __align__(16) short frag[2][4096];     // 2 x 8 KB staged frags
    const int blk = blockIdx.x;
    if (blk >= meta[17 + NE]) return;
    int e = 0;
    #pragma unroll 1
    while (blk >= meta[17 + e + 1]) ++e;
    const int lt = blk - meta[17 + e];
    const int cnt = meta[e];
    const int pbase = meta[8 + e];
    const int t = threadIdx.x, w = t >> 6, l = t & 63;
    const int lc = l & 31, lh = l >> 5;
    const int li = lt * 128 + w * 32 + lc;
    const int row = perm[pbase + min(li, cnt - 1)];
    float* hw = &hbuf[w][0][0];

// step source pointers (s is a literal -> folds at compile time)
#define SRC_H(s) ((s) < 8 ? W1H + e * 16384 + (s) * 2048 :                    \
                  (s) < 10 ? W2H + e * 4096 + ((s) & 1) * 2048 :              \
                  (s) < 12 ? W3H + e * 4096 + ((s) & 1) * 2048 :              \
                  (s) < 14 ? W4H + e * 4096 + ((s) & 1) * 2048 :              \
                  (s) < 16 ? W5H + e * 4096 + ((s) & 1) * 2048 :              \
                             W6H + e * 2048)
#define SRC_L(s) ((s) < 8 ? W1L + e * 16384 + (s) * 2048 :                    \
                  (s) < 10 ? W2L + e * 4096 + ((s) & 1) * 2048 :              \
                  (s) < 12 ? W3L + e * 4096 + ((s) & 1) * 2048 :              \
                  (s) < 14 ? W4L + e * 4096 + ((s) & 1) * 2048 :              \
                  (s) < 16 ? W5L + e * 4096 + ((s) & 1) * 2048 :              \
                             W6L + e * 2048)

    short8 g0, g1;
#define LOADG(s) { g0 = *(const short8*)(SRC_H(s) + t * 8);                   \
                   g1 = *(const short8*)(SRC_L(s) + t * 8); }
#define PUTG(b)  { *(short8*)(&frag[b][t * 8]) = g0;                          \
                   *(short8*)(&frag[b][2048 + t * 8]) = g1; }

#define MF3(AH, AL, BH, BL, C)                                                \
    C = MFMA32(AH, BH, C, 0, 0, 0);                                           \
    C = MFMA32(AL, BH, C, 0, 0, 0);                                           \
    C = MFMA32(AH, BL, C, 0, 0, 0);

    f32x16 c0 = {}, c1 = {};
    const f32x16 fz = {};

// layer-1 chunk step s (K slice [s*32, s*32+32)), frags from buf b
#define W1STEP(b, s) {                                                        \
    const float* xr = x + (size_t)row * DIM + (s) * 32 + lh * 8;              \
    _Pragma("unroll") for (int kk = 0; kk < 2; ++kk) {                        \
        float4 u0 = *(const float4*)(xr + kk * 16);                           \
        float4 u1 = *(const float4*)(xr + kk * 16 + 4);                       \
        float xs[8] = {u0.x, u0.y, u0.z, u0.w, u1.x, u1.y, u1.z, u1.w};       \
        short8 ah, al; split8v(xs, ah, al);                                   \
        short8 bh0 = *(const short8*)(&frag[b][(kk * 2 + 0) * 512 + l * 8]);  \
        short8 bl0 = *(const short8*)(&frag[b][2048 + (kk * 2 + 0) * 512 + l * 8]); \
        short8 bh1 = *(const short8*)(&frag[b][(kk * 2 + 1) * 512 + l * 8]);  \
        short8 bl1 = *(const short8*)(&frag[b][2048 + (kk * 2 + 1) * 512 + l * 8]); \
        MF3(ah, al, bh0, bl0, c0)                                             \
        MF3(ah, al, bh1, bl1, c1)                                             \
    } }

// hidden-layer half-step (K slice [hf*32, hf*32+32)), frags from buf b
#define HSTEP(b, hf) {                                                        \
    _Pragma("unroll") for (int kk = 0; kk < 2; ++kk) {                        \
        const float* ap = hw + lc * 66 + ((hf) * 2 + kk) * 16 + lh * 8;       \
        float4 u0 = *(const float4*)(ap);                                     \
        float4 u1 = *(const float4*)(ap + 4);                                 \
        float xs[8] = {u0.x, u0.y, u0.z, u0.w, u1.x, u1.y, u1.z, u1.w};       \
        short8 ah, al; split8v(xs, ah, al);                                   \
        short8 bh0 = *(const short8*)(&frag[b][(kk * 2 + 0) * 512 + l * 8]);  \
        short8 bl0 = *(const short8*)(&frag[b][2048 + (kk * 2 + 0) * 512 + l * 8]); \
        short8 bh1 = *(const short8*)(&frag[b][(kk * 2 + 1) * 512 + l * 8]);  \
        short8 bl1 = *(const short8*)(&frag[b][2048 + (kk * 2 + 1) * 512 + l * 8]); \
        MF3(ah, al, bh0, bl0, c0)                                             \
        MF3(ah, al, bh1, bl1, c1)                                             \
    } }

// D: col = lane&31, row = (reg&3) + 8*(reg>>2) + 4*(lane>>5)   [m74/m101]
#define WRITE16(biasp) {                                                      \
    const float* bp = (biasp);                                                \
    _Pragma("unroll") for (int nt = 0; nt < 2; ++nt) {                        \
        const f32x16& c = nt ? c1 : c0;                                       \
        float bv = bp[nt * 32 + lc];                                          \
        _Pragma("unroll") for (int r = 0; r < 16; ++r) {                      \
            int rw = (r & 3) + 8 * (r >> 2) + 4 * lh;                         \
            hw[rw * 66 + nt * 32 + lc] = fmaxf(c[r] + bv, 0.0f);              \
        } } }

    // ---- prologue: stage step 0, prefetch step 1 ----
    LOADG(0); PUTG(0); LOADG(1);
    __syncthreads();
    // ---- layer 1 (steps 0..7) ----
    W1STEP(0, 0)
    PUTG(1); LOADG(2);  __syncthreads(); W1STEP(1, 1)
    PUTG(0); LOADG(3);  __syncthreads(); W1STEP(0, 2)
    PUTG(1); LOADG(4);  __syncthreads(); W1STEP(1, 3)
    PUTG(0); LOADG(5);  __syncthreads(); W1STEP(0, 4)
    PUTG(1); LOADG(6);  __syncthreads(); W1STEP(1, 5)
    PUTG(0); LOADG(7);  __syncthreads(); W1STEP(0, 6)
    PUTG(1); LOADG(8);  __syncthreads(); W1STEP(1, 7)
    WRITE16(b1 + e * HID); c0 = fz; c1 = fz;
    // ---- layer 2 (steps 8,9) ----
    PUTG(0); LOADG(9);  __syncthreads(); HSTEP(0, 0)
    PUTG(1); LOADG(10); __syncthreads(); HSTEP(1, 1)
    WRITE16(b2 + e * HID); c0 = fz; c1 = fz;
    // ---- layer 3 (steps 10,11) ----
    PUTG(0); LOADG(11); __syncthreads(); HSTEP(0, 0)
    PUTG(1); LOADG(12); __syncthreads(); HSTEP(1, 1)
    WRITE16(b3 + e * HID); c0 = fz; c1 = fz;
    // ---- layer 4 (steps 12,13) ----
    PUTG(0); LOADG(13); __syncthreads(); HSTEP(0, 0)
    PUTG(1); LOADG(14); __syncthreads(); HSTEP(1, 1)
    WRITE16(b4 + e * HID); c0 = fz; c1 = fz;
    // ---- layer 5 (steps 14,15) ----
    PUTG(0); LOADG(15); __syncthreads(); HSTEP(0, 0)
    PUTG(1); LOADG(16); __syncthreads(); HSTEP(1, 1)
    WRITE16(b5 + e * HID); c0 = fz; c1 = fz;
    // ---- layer 6 (step 16): 4 ks x 1 nt ----
    PUTG(0); __syncthreads();
    {
        #pragma unroll
        for (int kk = 0; kk < 4; ++kk) {
            const float* ap = hw + lc * 66 + kk * 16 + lh * 8;
            float4 u0 = *(const float4*)(ap);
            float4 u1 = *(const float4*)(ap + 4);
            float xs[8] = {u0.x, u0.y, u0.z, u0.w, u1.x, u1.y, u1.z, u1.w};
            short8 ah, al; split8v(xs, ah, al);
            short8 bh = *(const short8*)(&frag[0][kk * 512 + l * 8]);
            short8 bl = *(const short8*)(&frag[0][2048 + kk * 512 + l * 8]);
            MF3(ah, al, bh, bl, c0)
        }
    }
    // write layer-6 result (cols 0..31) to hbuf, then scatter-store 18 cols
    #pragma unroll
    for (int r = 0; r < 16; ++r) {
        int rw = (r & 3) + 8 * (r >> 2) + 4 * lh;
        hw[rw * 66 + lc] = c0[r];
    }
    const float* b6p = b6 + e * NA;
    for (int i = l; i < 32 * NA; i += 64) {
        int rr = i / NA, cc = i % NA;
        int gr = lt * 128 + w * 32 + rr;
        if (gr < cnt)
            out[(size_t)perm[pbase + gr] * NA + cc] = hw[rr * 66 + cc] + b6p[cc];
    }
#undef SRC_H
#undef SRC_L
#undef LOADG
#undef PUTG
#undef MF3
#undef W1STEP
#undef HSTEP
#undef WRITE16
}

extern "C" void kernel_launch(void* const* d_in, const int* in_sizes, int n_in,
                              void* d_out, int out_size, void* d_ws, size_t ws_size,
                              hipStream_t stream) {
    const float* x  = (const float*)d_in[0];
    const int*   rm = (const int*)d_in[1];
    const float* W1 = (const float*)d_in[2];   const float* b1 = (const float*)d_in[3];
    const float* W2 = (const float*)d_in[4];   const float* b2 = (const float*)d_in[5];
    const float* W3 = (const float*)d_in[6];   const float* b3 = (const float*)d_in[7];
    const float* W4 = (const float*)d_in[8];   const float* b4 = (const float*)d_in[9];
    const float* W5 = (const float*)d_in[10];  const float* b5 = (const float*)d_in[11];
    const float* W6 = (const float*)d_in[12];  const float* b6 = (const float*)d_in[13];
    float* out = (float*)d_out;

    const int B = in_sizes[1];                 // 65536
    const int nblk = B / 256;                  // 256

    // ws layout:
    int* hist = (int*)d_ws;                    // nblk*8
    int* meta = hist + nblk * NE;              // 32
    int* perm = meta + 32;                     // B
    short* W1H = (short*)(perm + B);           // frag buffers
    short* W1L = W1H + 131072;
    short* W2H = W1L + 131072;  short* W2L = W2H + 32768;
    short* W3H = W2L + 32768;   short* W3L = W3H + 32768;
    short* W4H = W3L + 32768;   short* W4L = W4H + 32768;
    short* W5H = W4L + 32768;   short* W5L = W5H + 32768;
    short* W6H = W5L + 32768;   short* W6L = W6H + 16384;

    prep_histo<<<136 + nblk, 256, 0, stream>>>(W1, W2, W3, W4, W5, W6,
                                               W1H, W1L, W2H, W2L, W3H, W3L,
                                               W4H, W4L, W5H, W5L, W6H, W6L,
                                               rm, hist);
    scan_scatter<<<nblk, 512, 0, stream>>>(rm, hist, perm, meta);
    mlp_mfma<<<B / 128 + NE, 256, 0, stream>>>(x, perm, meta,
                                               W1H, W1L, W2H, W2L, W3H, W3L,
                                               W4H, W4L, W5H, W5L, W6H, W6L,
                                               b1, b2, b3, b4, b5, b6, out);
}